// Round 5
// baseline (44.120 us; speedup 1.0000x reference)
//
#include <hip/hip_runtime.h>
#include <hip/hip_bf16.h>

// BarlowTwins loss: logits[b,n,m] = sum_s z1[b,s,n]*z2[b,s,m]  (B=8, S=256, N=M=2048)
// loss = mean_{b,m}( LSE_n(logits[b,:,m]) - logits[b,m,m] )
//
// Round-5: unified 12-stage LDS pipeline (4 B-tiles + 8 A-tiles), one barrier/stage.
//  - 256 blocks (1/CU), 512 thr (8 waves), b = bid&7 (XCD-aligned, 4MB/XCD L2 set).
//  - B (z2, x log2e) staged through LDS cooperatively (all 8 waves load; wm-pair reads
//    frags) -> kills the serial per-lane B-prologue (768 dependent scalar ops, x2
//    wn-duplication) of round 4.
//  - Wave (wm,wn): 64 m (2 strips, 128 VGPR bf16 frags) x 256 n of each A-tile half.
//  - Stride-264 LDS rows: b128 write slot=(lane) and read slot=(col) both conflict-free
//    (measured 0 conflicts in rounds 2/4).
//  - Loads issued 2 stages ahead; store(t+1) then load(t+2) preserves apf ordering.
//  - No max tracking: acc init -96, exp2-sum; LSE-diag = ln2*(log2(S) - diag_acc).

#define NN 2048
#define SK 256
#define LDST 264
#define LOG2E 1.4426950408889634f
#define LN2   0.6931471805599453f
#define COFF  96.0f

typedef __attribute__((ext_vector_type(8))) short short8;
typedef __attribute__((ext_vector_type(16))) float f32x16;

__device__ __forceinline__ unsigned short f2bf(float f) {
    __hip_bfloat16 h = __float2bfloat16(f);
    unsigned short u; __builtin_memcpy(&u, &h, 2); return u;
}

__device__ __forceinline__ float exp2g(float x) {
#if __has_builtin(__builtin_amdgcn_exp2f)
    return __builtin_amdgcn_exp2f(x);
#else
    return exp2f(x);
#endif
}

__device__ __forceinline__ float log2g(float x) {
#if __has_builtin(__builtin_amdgcn_logf)
    return __builtin_amdgcn_logf(x);
#else
    return log2f(x);
#endif
}

__global__ __launch_bounds__(512, 2) void gemm_lse_kernel(
    const float* __restrict__ z1, const float* __restrict__ z2,
    float* __restrict__ ws_sum, float* __restrict__ ws_diag)
{
    __shared__ unsigned short lds[2][64 * LDST];   // 2 x 33.8 KB

    const int bid  = blockIdx.x;
    const int b    = bid & 7;
    const int tile = bid >> 3;
    const int mb   = tile & 7;         // 8 m-blocks of 256
    const int ns   = tile >> 3;        // 4 n-splits of 512
    const int tid  = threadIdx.x;
    const int lane = tid & 63;
    const int w    = tid >> 6;
    const int wm   = w >> 1;           // 0..3
    const int wn   = w & 1;            // 0..1
    const int col  = lane & 31;
    const int kg   = lane >> 5;

    const int m0    = mb * 256 + wm * 64;
    const int mcol0 = m0 + col;
    const int mcol1 = m0 + 32 + col;

    const float* z1b = z1 + (size_t)b * SK * NN;
    const float* z2b = z2 + (size_t)b * SK * NN;

    // ---- cooperative tile staging: 64 cols x 256 s, f32 -> bf16 -> LDS[col][s] ----
    float apf[4][8];
    auto load_T = [&](const float* src, int cbase) {
        #pragma unroll
        for (int r = 0; r < 4; ++r) {
            const int sg = 8 * r + w;  // s-group 0..31 (8 s each)
            const float* p = src + (size_t)(sg * 8) * NN + cbase + lane;
            #pragma unroll
            for (int j = 0; j < 8; ++j) apf[r][j] = p[(size_t)j * NN];
        }
    };
    auto store_A = [&](unsigned short* buf) {
        #pragma unroll
        for (int r = 0; r < 4; ++r) {
            const int sg = 8 * r + w;
            short8 pk;
            #pragma unroll
            for (int j = 0; j < 8; ++j) pk[j] = (short)f2bf(apf[r][j]);
            *(short8*)(buf + lane * LDST + sg * 8) = pk;
        }
    };
    auto store_B = [&](unsigned short* buf) {   // applies log2e scale
        #pragma unroll
        for (int r = 0; r < 4; ++r) {
            const int sg = 8 * r + w;
            short8 pk;
            #pragma unroll
            for (int j = 0; j < 8; ++j) pk[j] = (short)f2bf(apf[r][j] * LOG2E);
            *(short8*)(buf + lane * LDST + sg * 8) = pk;
        }
    };

    // ---- B phase: stage 4 B-tiles; wm-pair reads its 2 strips of frags ----
    short8 bf0[16], bf1[16];

    load_T(z2b, mb * 256);            // B0
    store_B(lds[0]);
    load_T(z2b, mb * 256 + 64);       // B1
    __syncthreads();

    #pragma unroll
    for (int j = 0; j < 4; ++j) {
        if (wm == j) {
            const unsigned short* b0 = lds[j & 1] + col * LDST + kg * 8;
            const unsigned short* b1 = lds[j & 1] + (32 + col) * LDST + kg * 8;
            #pragma unroll
            for (int ks = 0; ks < 16; ++ks) {
                bf0[ks] = *(const short8*)(b0 + ks * 16);
                bf1[ks] = *(const short8*)(b1 + ks * 16);
            }
        }
        if (j < 3) store_B(lds[(j + 1) & 1]);
        else       store_A(lds[0]);                      // A0 -> buf0
        if (j < 2) load_T(z2b, mb * 256 + (j + 2) * 64); // B2, B3
        else       load_T(z1b, ns * 512 + (j - 2) * 64); // A0, A1
        __syncthreads();
    }

    // ---- A phase: 8 tiles, compute buf[t&1] || store A[t+1] || load A[t+2] ----
    float srun0 = 0.0f, srun1 = 0.0f;

    #pragma unroll 2
    for (int t = 0; t < 8; ++t) {
        const unsigned short* abase = lds[t & 1] + (32 * wn + col) * LDST + kg * 8;

        f32x16 acc0, acc1;
        #pragma unroll
        for (int r = 0; r < 16; ++r) { acc0[r] = -COFF; acc1[r] = -COFF; }

        #pragma unroll
        for (int ks = 0; ks < 16; ++ks) {
            short8 af = *(const short8*)(abase + ks * 16);
            acc0 = __builtin_amdgcn_mfma_f32_32x32x16_bf16(af, bf0[ks], acc0, 0, 0, 0);
            acc1 = __builtin_amdgcn_mfma_f32_32x32x16_bf16(af, bf1[ks], acc1, 0, 0, 0);
        }

        if (t < 7) store_A(lds[(t + 1) & 1]);
        if (t < 6) load_T(z1b, ns * 512 + (t + 2) * 64);

        // diagonal capture (acc = logit' - 96; offset cancels in merge)
        const int nsub = ns * 512 + 64 * t + 32 * wn;
        if (nsub == m0) {
            #pragma unroll
            for (int r = 0; r < 16; ++r) {
                const int row = (r & 3) + 8 * (r >> 2) + 4 * kg;
                if (row == col) ws_diag[b * NN + mcol0] = acc0[r];
            }
        }
        if (nsub == m0 + 32) {
            #pragma unroll
            for (int r = 0; r < 16; ++r) {
                const int row = (r & 3) + 8 * (r >> 2) + 4 * kg;
                if (row == col) ws_diag[b * NN + mcol1] = acc1[r];
            }
        }

        // exp2-sum, 4 independent chains per strip
        {
            float e0 = 0, e1 = 0, e2 = 0, e3 = 0;
            #pragma unroll
            for (int r = 0; r < 16; r += 4) {
                e0 += exp2g(acc0[r]);     e1 += exp2g(acc0[r + 1]);
                e2 += exp2g(acc0[r + 2]); e3 += exp2g(acc0[r + 3]);
            }
            srun0 += (e0 + e1) + (e2 + e3);
        }
        {
            float e0 = 0, e1 = 0, e2 = 0, e3 = 0;
            #pragma unroll
            for (int r = 0; r < 16; r += 4) {
                e0 += exp2g(acc1[r]);     e1 += exp2g(acc1[r + 1]);
                e2 += exp2g(acc1[r + 2]); e3 += exp2g(acc1[r + 3]);
            }
            srun1 += (e0 + e1) + (e2 + e3);
        }

        __syncthreads();
    }

    srun0 += __shfl_xor(srun0, 32);
    srun1 += __shfl_xor(srun1, 32);
    if (kg == 0) {
        const int slot = ns * 2 + wn;   // 8 n-partials per (b,m)
        ws_sum[(b * 8 + slot) * NN + mcol0] = srun0;
        ws_sum[(b * 8 + slot) * NN + mcol1] = srun1;
    }
}

__global__ __launch_bounds__(256) void merge_kernel(
    const float* __restrict__ ws_sum, const float* __restrict__ ws_diag,
    float* __restrict__ partial)
{
    const int gid = blockIdx.x * 256 + threadIdx.x;   // 0..16383
    const int b = gid >> 11, m = gid & (NN - 1);

    float S = 0.0f;
    #pragma unroll
    for (int slot = 0; slot < 8; ++slot)
        S += ws_sum[(b * 8 + slot) * NN + m];
    float c = log2g(S) - ws_diag[gid];   // (LSE' - diag') in log2 units

    #pragma unroll
    for (int d = 1; d < 64; d <<= 1) c += __shfl_xor(c, d);
    __shared__ float red[4];
    if ((threadIdx.x & 63) == 0) red[threadIdx.x >> 6] = c;
    __syncthreads();
    if (threadIdx.x == 0)
        partial[blockIdx.x] = red[0] + red[1] + red[2] + red[3];
}

__global__ void final_kernel(const float* __restrict__ partial, float* __restrict__ out)
{
    float v = partial[threadIdx.x];   // 64 threads
    #pragma unroll
    for (int d = 1; d < 64; d <<= 1) v += __shfl_xor(v, d);
    if (threadIdx.x == 0) out[0] = v * (LN2 / 16384.0f);
}

extern "C" void kernel_launch(void* const* d_in, const int* in_sizes, int n_in,
                              void* d_out, int out_size, void* d_ws, size_t ws_size,
                              hipStream_t stream)
{
    const float* z1 = (const float*)d_in[0];
    const float* z2 = (const float*)d_in[1];
    float* ws  = (float*)d_ws;
    float* out = (float*)d_out;

    // ws layout (floats): sum[8][8][2048] | diag[8][2048] | partial[64]
    float* ws_sum  = ws;
    float* ws_diag = ws + 131072;
    float* ws_part = ws + 147456;

    gemm_lse_kernel<<<dim3(256), dim3(512), 0, stream>>>(z1, z2, ws_sum, ws_diag);
    merge_kernel<<<dim3(64), dim3(256), 0, stream>>>(ws_sum, ws_diag, ws_part);
    final_kernel<<<dim3(1), dim3(64), 0, stream>>>(ws_part, out);
}